// Round 9
// baseline (153.646 us; speedup 1.0000x reference)
//
#include <hip/hip_runtime.h>
#include <math.h>

#define NSITES 100000
#define NYEARS 20
#define HDIM 64

typedef __bf16 bf16x8 __attribute__((ext_vector_type(8)));
typedef float f32x4 __attribute__((ext_vector_type(4)));

__device__ __forceinline__ float sigmoidf_(float x) { return 1.0f / (1.0f + __expf(-x)); }
__device__ __forceinline__ float eluf_(float x) { return x > 0.0f ? x : expm1f(x); }

// load 8 consecutive f32 (32B-aligned) -> bf16x8 (RNE via __bf16 cast)
__device__ __forceinline__ bf16x8 cvt8_(const float* p) {
    float4 a = ((const float4*)p)[0];
    float4 b = ((const float4*)p)[1];
    bf16x8 r;
    r[0] = (__bf16)a.x; r[1] = (__bf16)a.y; r[2] = (__bf16)a.z; r[3] = (__bf16)a.w;
    r[4] = (__bf16)b.x; r[5] = (__bf16)b.y; r[6] = (__bf16)b.z; r[7] = (__bf16)b.w;
    return r;
}

__device__ __forceinline__ bf16x8 pack_bf_(f32x4 lo, f32x4 hi) {
    bf16x8 r;
    r[0] = (__bf16)lo[0]; r[1] = (__bf16)lo[1]; r[2] = (__bf16)lo[2]; r[3] = (__bf16)lo[3];
    r[4] = (__bf16)hi[0]; r[5] = (__bf16)hi[1]; r[6] = (__bf16)hi[2]; r[7] = (__bf16)hi[3];
    return r;
}

// One wave = TWO independent 16-site groups (G=2), ROLLED t-loop, no spill.
// Permuted-output-row MFMA recurrence (validated R5-R8):
//   pi(32kt+8q+4b+r)=16(2kt+b)+4q+r  => lane's D regs ARE its next B-fragment.
// R9 = conjunction of R6 (ILP=2) + R8 (L1I-resident rolled body) at
// __launch_bounds__(64,2) (256-reg budget; ~150 counted regs -> no spill).
__global__ __launch_bounds__(64, 2)
void rnet_kernel(const float* __restrict__ sxy0,
                 const float* __restrict__ sxy,
                 const float* __restrict__ oxy,
                 const float* __restrict__ W_h0, const float* __restrict__ b_h0,
                 const float* __restrict__ W_h1, const float* __restrict__ b_h1,
                 const float* __restrict__ W_ih, const float* __restrict__ b_ih,
                 const float* __restrict__ W_hh, const float* __restrict__ b_hh,
                 const float* __restrict__ W_psi0, const float* __restrict__ b_psi0,
                 const float* __restrict__ W_psi, const float* __restrict__ b_psi,
                 const float* __restrict__ W_p, const float* __restrict__ b_p,
                 float* __restrict__ out)
{
    const int lane = threadIdx.x;       // 0..63
    const int s = lane & 15;            // site within group / A-row within tile
    const int q = lane >> 4;            // quad
    const int sq = s >> 2, sr = s & 3;
    const int base = blockIdx.x * 32;   // NSITES = 3125*32 exactly
    const int site0 = base + s;
    const int site1 = base + 16 + s;

    __shared__ __align__(16) float xs_sh[32 * 19];    // per-site x values
    __shared__ __align__(16) float pL_sh[32 * 20];    // p logit of h_j at [site][j]
    __shared__ __align__(16) float psiL_sh[32 * 20];  // psi logit of h_j (slot 0 unused)
    __shared__ __align__(16) float psi0L_sh[32];      // psi0 logit of h0

    float* __restrict__ out_psi0 = out;                 // [N]
    float* __restrict__ out_psi  = out + NSITES;        // [N,19]
    float* __restrict__ out_p    = out + 20 * NSITES;   // [N,20,2]

    // ---- stage xs: 608 contiguous floats, coalesced ----
    {
        const float* src = sxy + (size_t)base * (NYEARS - 1);
#pragma unroll
        for (int r = 0; r < 10; ++r) {
            int i = r * 64 + lane;
            if (i < 32 * (NYEARS - 1)) xs_sh[i] = src[i];
        }
    }

    // ---- h0 stage for both groups ----
    bf16x8 bf[2][2];   // [group][kt]
    {
        float s0v[2];
        s0v[0] = sxy0[site0];
        s0v[1] = sxy0[site1];
        bf16x8 bf0[2][2];
#pragma unroll
        for (int kt = 0; kt < 2; ++kt) {
            const float* wp = W_h0 + kt * 32 + q * 8;
            const float* bp = b_h0 + kt * 32 + q * 8;
            float4 w0 = ((const float4*)wp)[0], w1 = ((const float4*)wp)[1];
            float4 c0 = ((const float4*)bp)[0], c1 = ((const float4*)bp)[1];
#pragma unroll
            for (int g = 0; g < 2; ++g) {
                const float sv = s0v[g];
                float v[8];
                v[0] = eluf_(fmaf(sv, w0.x, c0.x)); v[1] = eluf_(fmaf(sv, w0.y, c0.y));
                v[2] = eluf_(fmaf(sv, w0.z, c0.z)); v[3] = eluf_(fmaf(sv, w0.w, c0.w));
                v[4] = eluf_(fmaf(sv, w1.x, c1.x)); v[5] = eluf_(fmaf(sv, w1.y, c1.y));
                v[6] = eluf_(fmaf(sv, w1.z, c1.z)); v[7] = eluf_(fmaf(sv, w1.w, c1.w));
#pragma unroll
                for (int j = 0; j < 8; ++j) bf0[g][kt][j] = (__bf16)v[j];
            }
        }

        f32x4 acc[2][4];
#pragma unroll
        for (int mt = 0; mt < 4; ++mt) {
            const int dr = 32 * (mt >> 1) + 8 * q + 4 * (mt & 1);
            float4 b1 = *(const float4*)(b_h1 + dr);
#pragma unroll
            for (int g = 0; g < 2; ++g) {
                acc[g][mt][0] = b1.x; acc[g][mt][1] = b1.y;
                acc[g][mt][2] = b1.z; acc[g][mt][3] = b1.w;
            }
        }
#pragma unroll
        for (int kt = 0; kt < 2; ++kt)
#pragma unroll
            for (int mt = 0; mt < 4; ++mt) {
                const int ar = 32 * (mt >> 1) + 8 * sq + 4 * (mt & 1) + sr;
                bf16x8 a = cvt8_(W_h1 + ar * 64 + kt * 32 + q * 8);
#pragma unroll
                for (int g = 0; g < 2; ++g)
                    acc[g][mt] = __builtin_amdgcn_mfma_f32_16x16x32_bf16(a, bf0[g][kt], acc[g][mt], 0, 0, 0);
            }
#pragma unroll
        for (int g = 0; g < 2; ++g) {
            f32x4 e[4];
#pragma unroll
            for (int mt = 0; mt < 4; ++mt)
#pragma unroll
                for (int r = 0; r < 4; ++r) e[mt][r] = eluf_(acc[g][mt][r]);
            bf[g][0] = pack_bf_(e[0], e[1]);
            bf[g][1] = pack_bf_(e[2], e[3]);
        }
    }

    // ---- persistent loop state (after h0 to cap peak pressure) ----
    bf16x8 a_hh[4][2];
#pragma unroll
    for (int mt = 0; mt < 4; ++mt) {
        const int ar = 32 * (mt >> 1) + 8 * sq + 4 * (mt & 1) + sr;
#pragma unroll
        for (int kt = 0; kt < 2; ++kt)
            a_hh[mt][kt] = cvt8_(W_hh + ar * 64 + kt * 32 + q * 8);
    }
    bf16x8 a_head[2];
    {
        const float* hrow = (s == 1) ? W_p : ((s == 2) ? W_psi0 : W_psi);
#pragma unroll
        for (int kt = 0; kt < 2; ++kt) a_head[kt] = cvt8_(hrow + kt * 32 + q * 8);
    }
    f32x4 biasD[4], wihD[4];
#pragma unroll
    for (int mt = 0; mt < 4; ++mt) {
        const int dr = 32 * (mt >> 1) + 8 * q + 4 * (mt & 1);
        float4 bi = *(const float4*)(b_ih + dr);
        float4 bh = *(const float4*)(b_hh + dr);
        float4 wi = *(const float4*)(W_ih + dr);
        biasD[mt][0] = bi.x + bh.x; biasD[mt][1] = bi.y + bh.y;
        biasD[mt][2] = bi.z + bh.z; biasD[mt][3] = bi.w + bh.w;
        wihD[mt][0] = wi.x; wihD[mt][1] = wi.y; wihD[mt][2] = wi.z; wihD[mt][3] = wi.w;
    }
    f32x4 headC;
    headC[0] = (q == 0) ? b_psi[0]  : 0.0f;
    headC[1] = (q == 0) ? b_p[0]    : 0.0f;
    headC[2] = (q == 0) ? b_psi0[0] : 0.0f;
    headC[3] = 0.0f;

    // ---- recurrence: ROLLED, both groups interleaved per round ----
#pragma unroll 1
    for (int t = 1; t < NYEARS; ++t) {
        const float x0 = xs_sh[s * 19 + (t - 1)];
        const float x1 = xs_sh[(16 + s) * 19 + (t - 1)];

        f32x4 acc[2][4], accH[2];
#pragma unroll
        for (int mt = 0; mt < 4; ++mt) {
            acc[0][mt] = __builtin_amdgcn_mfma_f32_16x16x32_bf16(a_hh[mt][0], bf[0][0], biasD[mt], 0, 0, 0);
            acc[1][mt] = __builtin_amdgcn_mfma_f32_16x16x32_bf16(a_hh[mt][0], bf[1][0], biasD[mt], 0, 0, 0);
        }
        accH[0] = __builtin_amdgcn_mfma_f32_16x16x32_bf16(a_head[0], bf[0][0], headC, 0, 0, 0);
        accH[1] = __builtin_amdgcn_mfma_f32_16x16x32_bf16(a_head[0], bf[1][0], headC, 0, 0, 0);
#pragma unroll
        for (int mt = 0; mt < 4; ++mt) {
            acc[0][mt] = __builtin_amdgcn_mfma_f32_16x16x32_bf16(a_hh[mt][1], bf[0][1], acc[0][mt], 0, 0, 0);
            acc[1][mt] = __builtin_amdgcn_mfma_f32_16x16x32_bf16(a_hh[mt][1], bf[1][1], acc[1][mt], 0, 0, 0);
        }
        accH[0] = __builtin_amdgcn_mfma_f32_16x16x32_bf16(a_head[1], bf[0][1], accH[0], 0, 0, 0);
        accH[1] = __builtin_amdgcn_mfma_f32_16x16x32_bf16(a_head[1], bf[1][1], accH[1], 0, 0, 0);

#pragma unroll
        for (int g = 0; g < 2; ++g) {
            const float x = g ? x1 : x0;
            f32x4 hn[4];
#pragma unroll
            for (int mt = 0; mt < 4; ++mt)
#pragma unroll
                for (int r = 0; r < 4; ++r)
                    hn[mt][r] = fmaxf(fmaf(x, wihD[mt][r], acc[g][mt][r]), 0.0f);
            bf[g][0] = pack_bf_(hn[0], hn[1]);
            bf[g][1] = pack_bf_(hn[2], hn[3]);
        }

        if (q == 0) {
#pragma unroll
            for (int g = 0; g < 2; ++g) {
                const int ls = g * 16 + s;
                pL_sh[ls * 20 + (t - 1)]   = accH[g][1];
                psiL_sh[ls * 20 + (t - 1)] = accH[g][0];
                if (t == 1) psi0L_sh[ls] = accH[g][2];
            }
        }
    }

    // ---- final heads on h_19 ----
#pragma unroll
    for (int g = 0; g < 2; ++g) {
        f32x4 accH = __builtin_amdgcn_mfma_f32_16x16x32_bf16(a_head[0], bf[g][0], headC, 0, 0, 0);
        accH = __builtin_amdgcn_mfma_f32_16x16x32_bf16(a_head[1], bf[g][1], accH, 0, 0, 0);
        if (q == 0) {
            const int ls = g * 16 + s;
            pL_sh[ls * 20 + 19]   = accH[1];
            psiL_sh[ls * 20 + 19] = accH[0];
        }
    }

    __syncthreads();

    // ---- epilogue: sigmoid + oxy, coalesced ----
    const float wpo = W_p[HDIM];
    // psi0
    if (lane < 32) out_psi0[base + lane] = sigmoidf_(psi0L_sh[lane]);
    // psi: 32*19 = 608; out flat i = site_local*19 + c <- psiL_sh[sl*20 + c+1]
#pragma unroll
    for (int r = 0; r < 10; ++r) {
        int i = r * 64 + lane;
        if (i < 32 * 19) {
            int sl = i / 19, c = i - sl * 19;
            out_psi[(size_t)base * 19 + i] = sigmoidf_(psiL_sh[sl * 20 + c + 1]);
        }
    }
    // p: 32*40 = 1280 floats = 320 float4; float idx f -> logit pL_sh[f>>1]
    const float4* oxy_b = (const float4*)(oxy + (size_t)base * 40);
    float4* outp_b = (float4*)(out_p + (size_t)base * 40);
#pragma unroll
    for (int r = 0; r < 5; ++r) {
        int i4 = r * 64 + lane;            // [0,320)
        float4 ox = oxy_b[i4];
        float lg0 = pL_sh[i4 * 2];
        float lg1 = pL_sh[i4 * 2 + 1];
        float4 pv;
        pv.x = sigmoidf_(fmaf(wpo, ox.x, lg0));
        pv.y = sigmoidf_(fmaf(wpo, ox.y, lg0));
        pv.z = sigmoidf_(fmaf(wpo, ox.z, lg1));
        pv.w = sigmoidf_(fmaf(wpo, ox.w, lg1));
        outp_b[i4] = pv;
    }
}

extern "C" void kernel_launch(void* const* d_in, const int* in_sizes, int n_in,
                              void* d_out, int out_size, void* d_ws, size_t ws_size,
                              hipStream_t stream) {
    const float* sxy0   = (const float*)d_in[0];
    const float* sxy    = (const float*)d_in[1];
    const float* oxy    = (const float*)d_in[2];
    const float* W_h0   = (const float*)d_in[3];
    const float* b_h0   = (const float*)d_in[4];
    const float* W_h1   = (const float*)d_in[5];
    const float* b_h1   = (const float*)d_in[6];
    const float* W_ih   = (const float*)d_in[7];
    const float* b_ih   = (const float*)d_in[8];
    const float* W_hh   = (const float*)d_in[9];
    const float* b_hh   = (const float*)d_in[10];
    const float* W_psi0 = (const float*)d_in[11];
    const float* b_psi0 = (const float*)d_in[12];
    const float* W_psi  = (const float*)d_in[13];
    const float* b_psi  = (const float*)d_in[14];
    const float* W_p    = (const float*)d_in[15];
    const float* b_p    = (const float*)d_in[16];

    float* out = (float*)d_out;

    dim3 block(64);
    dim3 grid(NSITES / 32);   // 3125 waves, 32 sites each (2 groups of 16)
    rnet_kernel<<<grid, block, 0, stream>>>(
        sxy0, sxy, oxy, W_h0, b_h0, W_h1, b_h1, W_ih, b_ih, W_hh, b_hh,
        W_psi0, b_psi0, W_psi, b_psi, W_p, b_p, out);
}

// Round 10
// 144.948 us; speedup vs baseline: 1.0600x; 1.0600x over previous
//
#include <hip/hip_runtime.h>
#include <math.h>

#define NSITES 100000
#define NYEARS 20
#define HDIM 64
#define WSTR 72   // LDS weight row stride (bf16 elems); 144B: 16B-aligned, conflict-light

typedef __bf16 bf16x8 __attribute__((ext_vector_type(8)));
typedef float f32x4 __attribute__((ext_vector_type(4)));

__device__ __forceinline__ float sigmoidf_(float x) { return 1.0f / (1.0f + __expf(-x)); }
__device__ __forceinline__ float eluf_(float x) { return x > 0.0f ? x : expm1f(x); }

__device__ __forceinline__ unsigned pack2_(float a, float b) {
    union { __bf16 h; unsigned short u; } x, y;
    x.h = (__bf16)a; y.h = (__bf16)b;
    return ((unsigned)y.u << 16) | (unsigned)x.u;
}

// load 8 consecutive f32 (32B-aligned) -> bf16x8
__device__ __forceinline__ bf16x8 cvt8_(const float* p) {
    float4 a = ((const float4*)p)[0];
    float4 b = ((const float4*)p)[1];
    bf16x8 r;
    r[0] = (__bf16)a.x; r[1] = (__bf16)a.y; r[2] = (__bf16)a.z; r[3] = (__bf16)a.w;
    r[4] = (__bf16)b.x; r[5] = (__bf16)b.y; r[6] = (__bf16)b.z; r[7] = (__bf16)b.w;
    return r;
}

// read 8 bf16 (16B) from LDS weight tile at (row, col off)
__device__ __forceinline__ bf16x8 ldsfrag_(const unsigned short* b, int row, int off) {
    union { bf16x8 v; uint4 u; } r;
    r.u = *(const uint4*)&b[row * WSTR + off];
    return r.v;
}

__device__ __forceinline__ bf16x8 pack_bf_(f32x4 lo, f32x4 hi) {
    bf16x8 r;
    r[0] = (__bf16)lo[0]; r[1] = (__bf16)lo[1]; r[2] = (__bf16)lo[2]; r[3] = (__bf16)lo[3];
    r[4] = (__bf16)hi[0]; r[5] = (__bf16)hi[1]; r[6] = (__bf16)hi[2]; r[7] = (__bf16)hi[3];
    return r;
}

// 128-thread block = 2 waves x 16 sites. R10 change: W_hh/W_h1 staged ONCE per
// block into LDS (coalesced bf16), fragments gathered via ds_read_b128 --
// replaces the ~60 scattered L2-latency global loads per wave that R5-R9
// evidence says pinned the floor at ~55us. Permuted-output-row MFMA recurrence
// (validated R5-R9): pi(32kt+8q+4b+r)=16(2kt+b)+4q+r => lane's D regs ARE its
// next-round B-fragment (no LDS in t-loop). Logits overlay the W_h1 LDS
// region after h0 (barrier-protected).
__global__ __launch_bounds__(128)
void rnet_kernel(const float* __restrict__ sxy0,
                 const float* __restrict__ sxy,
                 const float* __restrict__ oxy,
                 const float* __restrict__ W_h0, const float* __restrict__ b_h0,
                 const float* __restrict__ W_h1, const float* __restrict__ b_h1,
                 const float* __restrict__ W_ih, const float* __restrict__ b_ih,
                 const float* __restrict__ W_hh, const float* __restrict__ b_hh,
                 const float* __restrict__ W_psi0, const float* __restrict__ b_psi0,
                 const float* __restrict__ W_psi, const float* __restrict__ b_psi,
                 const float* __restrict__ W_p, const float* __restrict__ b_p,
                 float* __restrict__ out)
{
    const int tid  = threadIdx.x;       // 0..127
    const int lane = tid & 63;
    const int wv   = tid >> 6;          // wave 0..1
    const int s = lane & 15;            // site within wave / A-row within tile
    const int q = lane >> 4;            // quad
    const int sq = s >> 2, sr = s & 3;
    const int base = blockIdx.x * 32;   // NSITES = 3125*32 exactly
    const int sl   = wv * 16 + s;       // site local 0..31
    const int site = base + sl;

    __shared__ __align__(16) unsigned short whh_l[64 * WSTR];  // bf16 W_hh
    __shared__ __align__(16) unsigned short wh1_l[64 * WSTR];  // bf16 W_h1; logits overlay after h0
    __shared__ __align__(16) float xs_sh[32 * 19];

    float* pL    = (float*)wh1_l;        // [32][20] raw p logits
    float* psiL  = pL + 640;             // [32][20] raw psi logits (slot0 unused)
    float* psi0L = psiL + 640;           // [32]

    float* __restrict__ out_psi0 = out;                 // [N]
    float* __restrict__ out_psi  = out + NSITES;        // [N,19]
    float* __restrict__ out_p    = out + 20 * NSITES;   // [N,20,2]

    // ==== stage weights (coalesced f32->bf16) + xs into LDS ====
    {
        const float4* whg = (const float4*)W_hh;
        const float4* w1g = (const float4*)W_h1;
#pragma unroll
        for (int j = 0; j < 8; ++j) {
            int e4 = j * 128 + tid;            // 0..1023 (1024 float4 = 64x64)
            int row = e4 >> 4, c4 = e4 & 15;
            float4 a = whg[e4];
            uint2 pa; pa.x = pack2_(a.x, a.y); pa.y = pack2_(a.z, a.w);
            *(uint2*)&whh_l[row * WSTR + c4 * 4] = pa;
            float4 b = w1g[e4];
            uint2 pb; pb.x = pack2_(b.x, b.y); pb.y = pack2_(b.z, b.w);
            *(uint2*)&wh1_l[row * WSTR + c4 * 4] = pb;
        }
        const float* src = sxy + (size_t)base * (NYEARS - 1);
#pragma unroll
        for (int r = 0; r < 5; ++r) {
            int i = r * 128 + tid;
            if (i < 32 * (NYEARS - 1)) xs_sh[i] = src[i];
        }
    }
    __syncthreads();

    // ==== h0 stage: hs = elu(s0*W_h0+b_h0) in B layout; h0 via permuted W_h1 (LDS) ====
    bf16x8 bf[2];
    {
        const float s0v = sxy0[site];
        bf16x8 bf0[2];
#pragma unroll
        for (int kt = 0; kt < 2; ++kt) {
            const float* wp = W_h0 + kt * 32 + q * 8;
            const float* bp = b_h0 + kt * 32 + q * 8;
            float4 w0 = ((const float4*)wp)[0], w1 = ((const float4*)wp)[1];
            float4 c0 = ((const float4*)bp)[0], c1 = ((const float4*)bp)[1];
            float v[8];
            v[0] = eluf_(fmaf(s0v, w0.x, c0.x)); v[1] = eluf_(fmaf(s0v, w0.y, c0.y));
            v[2] = eluf_(fmaf(s0v, w0.z, c0.z)); v[3] = eluf_(fmaf(s0v, w0.w, c0.w));
            v[4] = eluf_(fmaf(s0v, w1.x, c1.x)); v[5] = eluf_(fmaf(s0v, w1.y, c1.y));
            v[6] = eluf_(fmaf(s0v, w1.z, c1.z)); v[7] = eluf_(fmaf(s0v, w1.w, c1.w));
#pragma unroll
            for (int j = 0; j < 8; ++j) bf0[kt][j] = (__bf16)v[j];
        }

        f32x4 acc[4];
#pragma unroll
        for (int mt = 0; mt < 4; ++mt) {
            const int dr = 32 * (mt >> 1) + 8 * q + 4 * (mt & 1);
            float4 b1 = *(const float4*)(b_h1 + dr);
            acc[mt][0] = b1.x; acc[mt][1] = b1.y; acc[mt][2] = b1.z; acc[mt][3] = b1.w;
        }
#pragma unroll
        for (int kt = 0; kt < 2; ++kt)
#pragma unroll
            for (int mt = 0; mt < 4; ++mt) {
                const int ar = 32 * (mt >> 1) + 8 * sq + 4 * (mt & 1) + sr;
                bf16x8 a = ldsfrag_(wh1_l, ar, kt * 32 + q * 8);
                acc[mt] = __builtin_amdgcn_mfma_f32_16x16x32_bf16(a, bf0[kt], acc[mt], 0, 0, 0);
            }
        f32x4 e[4];
#pragma unroll
        for (int mt = 0; mt < 4; ++mt)
#pragma unroll
            for (int r = 0; r < 4; ++r) e[mt][r] = eluf_(acc[mt][r]);
        bf[0] = pack_bf_(e[0], e[1]);
        bf[1] = pack_bf_(e[2], e[3]);
    }

    // ==== persistent loop state: a_hh from LDS, small stuff direct ====
    bf16x8 a_hh[4][2];
#pragma unroll
    for (int mt = 0; mt < 4; ++mt) {
        const int ar = 32 * (mt >> 1) + 8 * sq + 4 * (mt & 1) + sr;
#pragma unroll
        for (int kt = 0; kt < 2; ++kt)
            a_hh[mt][kt] = ldsfrag_(whh_l, ar, kt * 32 + q * 8);
    }
    bf16x8 a_head[2];
    {
        const float* hrow = (s == 1) ? W_p : ((s == 2) ? W_psi0 : W_psi);
#pragma unroll
        for (int kt = 0; kt < 2; ++kt) a_head[kt] = cvt8_(hrow + kt * 32 + q * 8);
    }
    f32x4 biasD[4], wihD[4];
#pragma unroll
    for (int mt = 0; mt < 4; ++mt) {
        const int dr = 32 * (mt >> 1) + 8 * q + 4 * (mt & 1);
        float4 bi = *(const float4*)(b_ih + dr);
        float4 bh = *(const float4*)(b_hh + dr);
        float4 wi = *(const float4*)(W_ih + dr);
        biasD[mt][0] = bi.x + bh.x; biasD[mt][1] = bi.y + bh.y;
        biasD[mt][2] = bi.z + bh.z; biasD[mt][3] = bi.w + bh.w;
        wihD[mt][0] = wi.x; wihD[mt][1] = wi.y; wihD[mt][2] = wi.z; wihD[mt][3] = wi.w;
    }
    f32x4 headC;
    headC[0] = (q == 0) ? b_psi[0]  : 0.0f;
    headC[1] = (q == 0) ? b_p[0]    : 0.0f;
    headC[2] = (q == 0) ? b_psi0[0] : 0.0f;
    headC[3] = 0.0f;

    __syncthreads();   // all waves done reading wh1_l; logits may now overlay it

    // ==== recurrence: ROLLED. Round t: bf = h_{t-1} -> heads(h_{t-1}), h_t ====
#pragma unroll 1
    for (int t = 1; t < NYEARS; ++t) {
        const float x = xs_sh[sl * 19 + (t - 1)];

        f32x4 acc[4], accH;
#pragma unroll
        for (int mt = 0; mt < 4; ++mt)
            acc[mt] = __builtin_amdgcn_mfma_f32_16x16x32_bf16(a_hh[mt][0], bf[0], biasD[mt], 0, 0, 0);
        accH = __builtin_amdgcn_mfma_f32_16x16x32_bf16(a_head[0], bf[0], headC, 0, 0, 0);
#pragma unroll
        for (int mt = 0; mt < 4; ++mt)
            acc[mt] = __builtin_amdgcn_mfma_f32_16x16x32_bf16(a_hh[mt][1], bf[1], acc[mt], 0, 0, 0);
        accH = __builtin_amdgcn_mfma_f32_16x16x32_bf16(a_head[1], bf[1], accH, 0, 0, 0);

        f32x4 hn[4];
#pragma unroll
        for (int mt = 0; mt < 4; ++mt)
#pragma unroll
            for (int r = 0; r < 4; ++r)
                hn[mt][r] = fmaxf(fmaf(x, wihD[mt][r], acc[mt][r]), 0.0f);
        bf[0] = pack_bf_(hn[0], hn[1]);
        bf[1] = pack_bf_(hn[2], hn[3]);

        if (q == 0) {
            pL[sl * 20 + (t - 1)]   = accH[1];
            psiL[sl * 20 + (t - 1)] = accH[0];
            if (t == 1) psi0L[sl] = accH[2];
        }
    }

    // ==== final heads on h_19 ====
    {
        f32x4 accH = __builtin_amdgcn_mfma_f32_16x16x32_bf16(a_head[0], bf[0], headC, 0, 0, 0);
        accH = __builtin_amdgcn_mfma_f32_16x16x32_bf16(a_head[1], bf[1], accH, 0, 0, 0);
        if (q == 0) {
            pL[sl * 20 + 19]   = accH[1];
            psiL[sl * 20 + 19] = accH[0];
        }
    }

    __syncthreads();

    // ==== epilogue: sigmoid + oxy, 128 threads over 32 sites ====
    const float wpo = W_p[HDIM];
    if (tid < 32) out_psi0[base + tid] = sigmoidf_(psi0L[tid]);
    // psi: 32*19 = 608; out flat i = sl*19 + c <- psiL[sl*20 + c+1]
#pragma unroll
    for (int r = 0; r < 5; ++r) {
        int i = r * 128 + tid;
        if (i < 32 * 19) {
            int s2 = i / 19, c = i - s2 * 19;
            out_psi[(size_t)base * 19 + i] = sigmoidf_(psiL[s2 * 20 + c + 1]);
        }
    }
    // p: 32*40 = 1280 floats = 320 float4; float idx f -> logit pL[f>>1]
    const float4* oxy_b = (const float4*)(oxy + (size_t)base * 40);
    float4* outp_b = (float4*)(out_p + (size_t)base * 40);
#pragma unroll
    for (int r = 0; r < 3; ++r) {
        int i4 = r * 128 + tid;
        if (i4 < 320) {
            float4 ox = oxy_b[i4];
            float lg0 = pL[i4 * 2];
            float lg1 = pL[i4 * 2 + 1];
            float4 pv;
            pv.x = sigmoidf_(fmaf(wpo, ox.x, lg0));
            pv.y = sigmoidf_(fmaf(wpo, ox.y, lg0));
            pv.z = sigmoidf_(fmaf(wpo, ox.z, lg1));
            pv.w = sigmoidf_(fmaf(wpo, ox.w, lg1));
            outp_b[i4] = pv;
        }
    }
}

extern "C" void kernel_launch(void* const* d_in, const int* in_sizes, int n_in,
                              void* d_out, int out_size, void* d_ws, size_t ws_size,
                              hipStream_t stream) {
    const float* sxy0   = (const float*)d_in[0];
    const float* sxy    = (const float*)d_in[1];
    const float* oxy    = (const float*)d_in[2];
    const float* W_h0   = (const float*)d_in[3];
    const float* b_h0   = (const float*)d_in[4];
    const float* W_h1   = (const float*)d_in[5];
    const float* b_h1   = (const float*)d_in[6];
    const float* W_ih   = (const float*)d_in[7];
    const float* b_ih   = (const float*)d_in[8];
    const float* W_hh   = (const float*)d_in[9];
    const float* b_hh   = (const float*)d_in[10];
    const float* W_psi0 = (const float*)d_in[11];
    const float* b_psi0 = (const float*)d_in[12];
    const float* W_psi  = (const float*)d_in[13];
    const float* b_psi  = (const float*)d_in[14];
    const float* W_p    = (const float*)d_in[15];
    const float* b_p    = (const float*)d_in[16];

    float* out = (float*)d_out;

    dim3 block(128);
    dim3 grid(NSITES / 32);   // 3125 blocks, 2 waves x 16 sites each
    rnet_kernel<<<grid, block, 0, stream>>>(
        sxy0, sxy, oxy, W_h0, b_h0, W_h1, b_h1, W_ih, b_ih, W_hh, b_hh,
        W_psi0, b_psi0, W_psi, b_psi, W_p, b_p, out);
}

// Round 12
// 138.078 us; speedup vs baseline: 1.1127x; 1.0498x over previous
//
#include <hip/hip_runtime.h>
#include <math.h>

#define NSITES 100000
#define NYEARS 20
#define HDIM 64
#define WSTR 72   // LDS weight row stride (bf16 elems); 144B, 16B-aligned

typedef __bf16 bf16x8 __attribute__((ext_vector_type(8)));
typedef float f32x4 __attribute__((ext_vector_type(4)));

__device__ __forceinline__ float sigmoidf_(float x) { return 1.0f / (1.0f + __expf(-x)); }
__device__ __forceinline__ float eluf_(float x) { return x > 0.0f ? x : expm1f(x); }

__device__ __forceinline__ unsigned pack2_(float a, float b) {
    union { __bf16 h; unsigned short u; } x, y;
    x.h = (__bf16)a; y.h = (__bf16)b;
    return ((unsigned)y.u << 16) | (unsigned)x.u;
}

// load 8 consecutive f32 (32B-aligned) -> bf16x8
__device__ __forceinline__ bf16x8 cvt8_(const float* p) {
    float4 a = ((const float4*)p)[0];
    float4 b = ((const float4*)p)[1];
    bf16x8 r;
    r[0] = (__bf16)a.x; r[1] = (__bf16)a.y; r[2] = (__bf16)a.z; r[3] = (__bf16)a.w;
    r[4] = (__bf16)b.x; r[5] = (__bf16)b.y; r[6] = (__bf16)b.z; r[7] = (__bf16)b.w;
    return r;
}

// read 8 bf16 (16B) from LDS weight tile at (row, col off)
__device__ __forceinline__ bf16x8 ldsfrag_(const unsigned short* b, int row, int off) {
    union { bf16x8 v; uint4 u; } r;
    r.u = *(const uint4*)&b[row * WSTR + off];
    return r.v;
}

__device__ __forceinline__ bf16x8 pack_bf_(f32x4 lo, f32x4 hi) {
    bf16x8 r;
    r[0] = (__bf16)lo[0]; r[1] = (__bf16)lo[1]; r[2] = (__bf16)lo[2]; r[3] = (__bf16)lo[3];
    r[4] = (__bf16)hi[0]; r[5] = (__bf16)hi[1]; r[6] = (__bf16)hi[2]; r[7] = (__bf16)hi[3];
    return r;
}

// 256-thread block = 4 waves x 16 sites (64 sites/block, 1563 blocks).
// R12 = R11 with DEDICATED logit LDS (R11 overlaid logits on whh_l: 10.5KB of
// logits vs 9.2KB region + compiler-reorderable LDS layout -> xs_sh corruption
// -> psi absmax 0.75). Loop body = validated R8/R10: rolled t-loop,
// permuted-output-row MFMA recurrence pi(32kt+8q+4b+r)=16(2kt+b)+4q+r (lane's
// D regs ARE its next-round B-fragment), heads as 5th m-tile, xs pipelined.
__global__ __launch_bounds__(256, 2)
void rnet_kernel(const float* __restrict__ sxy0,
                 const float* __restrict__ sxy,
                 const float* __restrict__ oxy,
                 const float* __restrict__ W_h0, const float* __restrict__ b_h0,
                 const float* __restrict__ W_h1, const float* __restrict__ b_h1,
                 const float* __restrict__ W_ih, const float* __restrict__ b_ih,
                 const float* __restrict__ W_hh, const float* __restrict__ b_hh,
                 const float* __restrict__ W_psi0, const float* __restrict__ b_psi0,
                 const float* __restrict__ W_psi, const float* __restrict__ b_psi,
                 const float* __restrict__ W_p, const float* __restrict__ b_p,
                 float* __restrict__ out)
{
    const int tid  = threadIdx.x;       // 0..255
    const int lane = tid & 63;
    const int wv   = tid >> 6;          // wave 0..3
    const int s = lane & 15;            // site within wave / A-row within tile
    const int q = lane >> 4;            // quad
    const int sq = s >> 2, sr = s & 3;
    const int base = blockIdx.x * 64;   // 1563 blocks; last block partial
    const int sl   = wv * 16 + s;       // site local 0..63
    const int site = base + sl;
    const int site_ld = site < NSITES ? site : NSITES - 1;   // clamped for loads

    __shared__ __align__(16) unsigned short whh_l[64 * WSTR];  // bf16 W_hh
    __shared__ __align__(16) unsigned short wh1_l[64 * WSTR];  // bf16 W_h1
    __shared__ __align__(16) float xs_sh[64 * 19];
    __shared__ __align__(16) float pL[64 * 20];     // raw p logits [site][j]
    __shared__ __align__(16) float psiL[64 * 20];   // raw psi logits (slot0 unused)
    __shared__ __align__(16) float psi0L[64];       // psi0 logit of h0

    float* __restrict__ out_psi0 = out;                 // [N]
    float* __restrict__ out_psi  = out + NSITES;        // [N,19]
    float* __restrict__ out_p    = out + 20 * NSITES;   // [N,20,2]

    // ==== stage weights (coalesced f32->bf16) + xs into LDS ====
    {
        const float4* whg = (const float4*)W_hh;
        const float4* w1g = (const float4*)W_h1;
#pragma unroll
        for (int j = 0; j < 4; ++j) {
            int e4 = j * 256 + tid;            // 0..1023 (1024 float4 = 64x64)
            int row = e4 >> 4, c4 = e4 & 15;
            float4 a = whg[e4];
            uint2 pa; pa.x = pack2_(a.x, a.y); pa.y = pack2_(a.z, a.w);
            *(uint2*)&whh_l[row * WSTR + c4 * 4] = pa;
            float4 b = w1g[e4];
            uint2 pb; pb.x = pack2_(b.x, b.y); pb.y = pack2_(b.z, b.w);
            *(uint2*)&wh1_l[row * WSTR + c4 * 4] = pb;
        }
        // xs: 64*19 = 1216 floats; clamp per-site row for tail block
#pragma unroll
        for (int r = 0; r < 5; ++r) {
            int i = r * 256 + tid;
            if (i < 64 * 19) {
                int srow = i / 19, c = i - srow * 19;
                int gsite = base + srow; if (gsite >= NSITES) gsite = NSITES - 1;
                xs_sh[i] = sxy[(size_t)gsite * 19 + c];
            }
        }
    }
    __syncthreads();

    // ==== h0 stage: hs = elu(s0*W_h0+b_h0) in B layout; h0 via permuted W_h1 (LDS) ====
    bf16x8 bf[2];
    {
        const float s0v = sxy0[site_ld];
        bf16x8 bf0[2];
#pragma unroll
        for (int kt = 0; kt < 2; ++kt) {
            const float* wp = W_h0 + kt * 32 + q * 8;
            const float* bp = b_h0 + kt * 32 + q * 8;
            float4 w0 = ((const float4*)wp)[0], w1 = ((const float4*)wp)[1];
            float4 c0 = ((const float4*)bp)[0], c1 = ((const float4*)bp)[1];
            float v[8];
            v[0] = eluf_(fmaf(s0v, w0.x, c0.x)); v[1] = eluf_(fmaf(s0v, w0.y, c0.y));
            v[2] = eluf_(fmaf(s0v, w0.z, c0.z)); v[3] = eluf_(fmaf(s0v, w0.w, c0.w));
            v[4] = eluf_(fmaf(s0v, w1.x, c1.x)); v[5] = eluf_(fmaf(s0v, w1.y, c1.y));
            v[6] = eluf_(fmaf(s0v, w1.z, c1.z)); v[7] = eluf_(fmaf(s0v, w1.w, c1.w));
#pragma unroll
            for (int j = 0; j < 8; ++j) bf0[kt][j] = (__bf16)v[j];
        }

        f32x4 acc[4];
#pragma unroll
        for (int mt = 0; mt < 4; ++mt) {
            const int dr = 32 * (mt >> 1) + 8 * q + 4 * (mt & 1);
            float4 b1 = *(const float4*)(b_h1 + dr);
            acc[mt][0] = b1.x; acc[mt][1] = b1.y; acc[mt][2] = b1.z; acc[mt][3] = b1.w;
        }
#pragma unroll
        for (int kt = 0; kt < 2; ++kt)
#pragma unroll
            for (int mt = 0; mt < 4; ++mt) {
                const int ar = 32 * (mt >> 1) + 8 * sq + 4 * (mt & 1) + sr;
                bf16x8 a = ldsfrag_(wh1_l, ar, kt * 32 + q * 8);
                acc[mt] = __builtin_amdgcn_mfma_f32_16x16x32_bf16(a, bf0[kt], acc[mt], 0, 0, 0);
            }
        f32x4 e[4];
#pragma unroll
        for (int mt = 0; mt < 4; ++mt)
#pragma unroll
            for (int r = 0; r < 4; ++r) e[mt][r] = eluf_(acc[mt][r]);
        bf[0] = pack_bf_(e[0], e[1]);
        bf[1] = pack_bf_(e[2], e[3]);
    }

    // ==== persistent loop state: a_hh from LDS, small stuff direct ====
    bf16x8 a_hh[4][2];
#pragma unroll
    for (int mt = 0; mt < 4; ++mt) {
        const int ar = 32 * (mt >> 1) + 8 * sq + 4 * (mt & 1) + sr;
#pragma unroll
        for (int kt = 0; kt < 2; ++kt)
            a_hh[mt][kt] = ldsfrag_(whh_l, ar, kt * 32 + q * 8);
    }
    bf16x8 a_head[2];
    {
        const float* hrow = (s == 1) ? W_p : ((s == 2) ? W_psi0 : W_psi);
#pragma unroll
        for (int kt = 0; kt < 2; ++kt) a_head[kt] = cvt8_(hrow + kt * 32 + q * 8);
    }
    f32x4 biasD[4], wihD[4];
#pragma unroll
    for (int mt = 0; mt < 4; ++mt) {
        const int dr = 32 * (mt >> 1) + 8 * q + 4 * (mt & 1);
        float4 bi = *(const float4*)(b_ih + dr);
        float4 bh = *(const float4*)(b_hh + dr);
        float4 wi = *(const float4*)(W_ih + dr);
        biasD[mt][0] = bi.x + bh.x; biasD[mt][1] = bi.y + bh.y;
        biasD[mt][2] = bi.z + bh.z; biasD[mt][3] = bi.w + bh.w;
        wihD[mt][0] = wi.x; wihD[mt][1] = wi.y; wihD[mt][2] = wi.z; wihD[mt][3] = wi.w;
    }
    f32x4 headC;
    headC[0] = (q == 0) ? b_psi[0]  : 0.0f;
    headC[1] = (q == 0) ? b_p[0]    : 0.0f;
    headC[2] = (q == 0) ? b_psi0[0] : 0.0f;
    headC[3] = 0.0f;

    // ==== recurrence: ROLLED, xs read pipelined one round ahead ====
    float x = xs_sh[sl * 19];          // x for round t=1
#pragma unroll 1
    for (int t = 1; t < NYEARS; ++t) {
        float x_next = (t < NYEARS - 1) ? xs_sh[sl * 19 + t] : 0.0f;

        f32x4 acc[4], accH;
#pragma unroll
        for (int mt = 0; mt < 4; ++mt)
            acc[mt] = __builtin_amdgcn_mfma_f32_16x16x32_bf16(a_hh[mt][0], bf[0], biasD[mt], 0, 0, 0);
        accH = __builtin_amdgcn_mfma_f32_16x16x32_bf16(a_head[0], bf[0], headC, 0, 0, 0);
#pragma unroll
        for (int mt = 0; mt < 4; ++mt)
            acc[mt] = __builtin_amdgcn_mfma_f32_16x16x32_bf16(a_hh[mt][1], bf[1], acc[mt], 0, 0, 0);
        accH = __builtin_amdgcn_mfma_f32_16x16x32_bf16(a_head[1], bf[1], accH, 0, 0, 0);

        f32x4 hn[4];
#pragma unroll
        for (int mt = 0; mt < 4; ++mt)
#pragma unroll
            for (int r = 0; r < 4; ++r)
                hn[mt][r] = fmaxf(fmaf(x, wihD[mt][r], acc[mt][r]), 0.0f);
        bf[0] = pack_bf_(hn[0], hn[1]);
        bf[1] = pack_bf_(hn[2], hn[3]);

        if (q == 0) {
            pL[sl * 20 + (t - 1)]   = accH[1];
            psiL[sl * 20 + (t - 1)] = accH[0];
            if (t == 1) psi0L[sl] = accH[2];
        }
        x = x_next;
    }

    // ==== final heads on h_19 ====
    {
        f32x4 accH = __builtin_amdgcn_mfma_f32_16x16x32_bf16(a_head[0], bf[0], headC, 0, 0, 0);
        accH = __builtin_amdgcn_mfma_f32_16x16x32_bf16(a_head[1], bf[1], accH, 0, 0, 0);
        if (q == 0) {
            pL[sl * 20 + 19]   = accH[1];
            psiL[sl * 20 + 19] = accH[0];
        }
    }

    __syncthreads();

    // ==== epilogue: sigmoid + oxy, 256 threads over 64 sites, guarded ====
    const float wpo = W_p[HDIM];
    if (tid < 64 && base + tid < NSITES) out_psi0[base + tid] = sigmoidf_(psi0L[tid]);
    // psi: 64*19 = 1216; out flat i = sl*19 + c <- psiL[sl*20 + c+1]
#pragma unroll
    for (int r = 0; r < 5; ++r) {
        int i = r * 256 + tid;
        if (i < 64 * 19 && (size_t)base * 19 + i < (size_t)NSITES * 19) {
            int s2 = i / 19, c = i - s2 * 19;
            out_psi[(size_t)base * 19 + i] = sigmoidf_(psiL[s2 * 20 + c + 1]);
        }
    }
    // p: 64*40 = 2560 floats = 640 float4; float idx f -> logit pL[f>>1]
    const float4* oxy_b = (const float4*)(oxy + (size_t)base * 40);
    float4* outp_b = (float4*)(out_p + (size_t)base * 40);
    const int p4max = (NSITES * 40) / 4;   // global float4 bound
#pragma unroll
    for (int r = 0; r < 3; ++r) {
        int i4 = r * 256 + tid;
        if (i4 < 640 && blockIdx.x * 640 + i4 < p4max) {
            float4 ox = oxy_b[i4];
            float lg0 = pL[i4 * 2];
            float lg1 = pL[i4 * 2 + 1];
            float4 pv;
            pv.x = sigmoidf_(fmaf(wpo, ox.x, lg0));
            pv.y = sigmoidf_(fmaf(wpo, ox.y, lg0));
            pv.z = sigmoidf_(fmaf(wpo, ox.z, lg1));
            pv.w = sigmoidf_(fmaf(wpo, ox.w, lg1));
            outp_b[i4] = pv;
        }
    }
}

extern "C" void kernel_launch(void* const* d_in, const int* in_sizes, int n_in,
                              void* d_out, int out_size, void* d_ws, size_t ws_size,
                              hipStream_t stream) {
    const float* sxy0   = (const float*)d_in[0];
    const float* sxy    = (const float*)d_in[1];
    const float* oxy    = (const float*)d_in[2];
    const float* W_h0   = (const float*)d_in[3];
    const float* b_h0   = (const float*)d_in[4];
    const float* W_h1   = (const float*)d_in[5];
    const float* b_h1   = (const float*)d_in[6];
    const float* W_ih   = (const float*)d_in[7];
    const float* b_ih   = (const float*)d_in[8];
    const float* W_hh   = (const float*)d_in[9];
    const float* b_hh   = (const float*)d_in[10];
    const float* W_psi0 = (const float*)d_in[11];
    const float* b_psi0 = (const float*)d_in[12];
    const float* W_psi  = (const float*)d_in[13];
    const float* b_psi  = (const float*)d_in[14];
    const float* W_p    = (const float*)d_in[15];
    const float* b_p    = (const float*)d_in[16];

    float* out = (float*)d_out;

    dim3 block(256);
    dim3 grid((NSITES + 63) / 64);   // 1563 blocks, 4 waves x 16 sites each
    rnet_kernel<<<grid, block, 0, stream>>>(
        sxy0, sxy, oxy, W_h0, b_h0, W_h1, b_h1, W_ih, b_ih, W_hh, b_hh,
        W_psi0, b_psi0, W_psi, b_psi, W_p, b_p, out);
}